// Round 1
// baseline (795.326 us; speedup 1.0000x reference)
//
#include <hip/hip_runtime.h>
#include <hip/hip_bf16.h>

typedef __bf16 bf16_t;
typedef __bf16 bf16x8 __attribute__((ext_vector_type(8)));
typedef __bf16 bf16x4 __attribute__((ext_vector_type(4)));
typedef float  f32x4  __attribute__((ext_vector_type(4)));

#define NB 8
#define CD 2048
#define BD 2048
#define LD 2048  // row stride (elements) for every 2048x2048 slice

// ---------------- X [N,C,B] f32 -> XbT [N,B,C] bf16 (transpose + convert) ----------------
__global__ void k_transpose_x(const float* __restrict__ X, bf16_t* __restrict__ XbT) {
    __shared__ bf16_t tile[64][66];  // pad 2 -> 33-word row stride, conflict-free transpose read
    const int t = threadIdx.x;
    const int b0 = blockIdx.x * 64, c0 = blockIdx.y * 64, n = blockIdx.z;
    const float* Xn = X + (size_t)n * CD * BD;
    bf16_t* Tn = XbT + (size_t)n * BD * CD;
    const int cl = t & 63, rw = t >> 6;
#pragma unroll
    for (int r = 0; r < 16; ++r) {
        int row = r * 4 + rw;
        tile[row][cl] = (bf16_t)Xn[(size_t)(c0 + row) * BD + b0 + cl];
    }
    __syncthreads();
#pragma unroll
    for (int r = 0; r < 16; ++r) {
        int row = r * 4 + rw;
        Tn[(size_t)(b0 + row) * CD + c0 + cl] = tile[cl][row];
    }
}

// ---------------- Wk/Wq f32 -> bf16 ----------------
__global__ void k_convert_w(const float* __restrict__ Wk, const float* __restrict__ Wq,
                            bf16_t* __restrict__ Wkb, bf16_t* __restrict__ Wqb) {
    const size_t i = ((size_t)blockIdx.x * 256 + threadIdx.x) * 4;
    const float* src = blockIdx.y ? Wq : Wk;
    bf16_t* dst = blockIdx.y ? Wqb : Wkb;
    float4 v = *(const float4*)(src + i);
    bf16x4 o;
    o[0] = (bf16_t)v.x; o[1] = (bf16_t)v.y; o[2] = (bf16_t)v.z; o[3] = (bf16_t)v.w;
    *(bf16x4*)(dst + i) = o;
}

// ---------------- NT GEMM: C[M,N] = A[M,K](rm) * B[N,K](rm)^T, bf16 in, f32 acc ----------
// m97 structure: 128x128 tile, 4 waves (each 64x64), BK=32, global_load_lds width 16,
// 2 barriers per K-step, 16x16x32 bf16 MFMA. Linear LDS (T2 swizzle is null at 2-phase).
__device__ __forceinline__ void stage_tile(const bf16_t* gsrc, bf16_t* ldsbase, int wave, int lane) {
#pragma unroll
    for (int q = 0; q < 2; ++q) {
        const int r = q * 64 + wave * 16 + (lane >> 2);  // tile row this lane feeds
        const int s = lane & 3;                          // 16B slot within 64B row
        const bf16_t* g = gsrc + (size_t)r * LD + s * 8;
        bf16_t* l = ldsbase + q * 2048 + wave * 512;     // wave-uniform LDS base (+lane*16 by HW)
        __builtin_amdgcn_global_load_lds((const __attribute__((address_space(1))) void*)g,
                                         (__attribute__((address_space(3))) void*)l, 16, 0, 0);
    }
}

template <int EPI>  // 0: f32 store; 1: +bias[row], bf16 store
__global__ __launch_bounds__(256) void k_gemm_nt(const bf16_t* __restrict__ Aall, size_t sA,
                                                 const bf16_t* __restrict__ Ball, size_t sB,
                                                 void* __restrict__ Call, size_t sC,
                                                 const float* __restrict__ bias) {
    __shared__ alignas(16) bf16_t As[128 * 32];
    __shared__ alignas(16) bf16_t Bs[128 * 32];
    const int t = threadIdx.x;
    const int lane = t & 63, wave = t >> 6;
    const int z = blockIdx.z;
    const int m0 = blockIdx.y * 128, n0 = blockIdx.x * 128;
    const bf16_t* Abase = Aall + sA * z + (size_t)m0 * LD;
    const bf16_t* Bbase = Ball + sB * z + (size_t)n0 * LD;

    const int wr = wave >> 1, wc = wave & 1;     // wave -> 64x64 quadrant
    const int lr = lane & 15, kslot = lane >> 4; // fragment lane decomposition

    f32x4 acc[4][4] = {};

    for (int kt = 0; kt < LD; kt += 32) {
        __syncthreads();  // previous tile fully consumed
        stage_tile(Abase + kt, As, wave, lane);
        stage_tile(Bbase + kt, Bs, wave, lane);
        __syncthreads();  // compiler drains vmcnt(0) before s_barrier

        bf16x8 afr[4], bfr[4];
#pragma unroll
        for (int mi = 0; mi < 4; ++mi) {
            const int r = wr * 64 + mi * 16 + lr;
            afr[mi] = *(const bf16x8*)(As + r * 32 + kslot * 8);
        }
#pragma unroll
        for (int ni = 0; ni < 4; ++ni) {
            const int r = wc * 64 + ni * 16 + lr;
            bfr[ni] = *(const bf16x8*)(Bs + r * 32 + kslot * 8);
        }
#pragma unroll
        for (int mi = 0; mi < 4; ++mi)
#pragma unroll
            for (int ni = 0; ni < 4; ++ni)
                acc[mi][ni] = __builtin_amdgcn_mfma_f32_16x16x32_bf16(afr[mi], bfr[ni], acc[mi][ni], 0, 0, 0);
    }

    // epilogue: C/D layout col=lane&15, row=(lane>>4)*4+j (HW-verified mapping)
    const int rowb = m0 + wr * 64;
    const int colb = n0 + wc * 64 + lr;
    const int rsub = kslot * 4;
#pragma unroll
    for (int mi = 0; mi < 4; ++mi) {
#pragma unroll
        for (int j = 0; j < 4; ++j) {
            const int r = rowb + mi * 16 + rsub + j;
            float bv = 0.f;
            if (EPI == 1) bv = bias[r];
#pragma unroll
            for (int ni = 0; ni < 4; ++ni) {
                const int c = colb + ni * 16;
                const float v = acc[mi][ni][j] + bv;
                if (EPI == 1) ((bf16_t*)Call)[sC * z + (size_t)r * LD + c] = (bf16_t)v;
                else          ((float*)Call)[sC * z + (size_t)r * LD + c] = v;
            }
        }
    }
}

// ---------------- squared row norms of Kb/Qb (bf16 [N,C,B]) -> f32 [N,C] ----------------
__global__ void k_row_norm2(const bf16_t* __restrict__ Kb, const bf16_t* __restrict__ Qb,
                            float* __restrict__ DK2, float* __restrict__ DQ2) {
    const int row = blockIdx.x, n = blockIdx.y;
    const bf16_t* src = blockIdx.z ? Qb : Kb;
    float* dst = blockIdx.z ? DQ2 : DK2;
    const bf16_t* pr = src + ((size_t)n * CD + row) * BD + threadIdx.x * 8;
    bf16x8 v = *(const bf16x8*)pr;
    float s = 0.f;
#pragma unroll
    for (int e = 0; e < 8; ++e) { float x = (float)v[e]; s += x * x; }
#pragma unroll
    for (int off = 32; off; off >>= 1) s += __shfl_xor(s, off, 64);
    __shared__ float ws[4];
    if ((threadIdx.x & 63) == 0) ws[threadIdx.x >> 6] = s;
    __syncthreads();
    if (threadIdx.x == 0) dst[(size_t)n * CD + row] = ws[0] + ws[1] + ws[2] + ws[3];
}

// ------- per-row: scale by rsqrt(DQ2[i]*DK2[j]), softmax over i, write bf16 SMT[j,i] -------
__global__ void k_softmax_rows(const float* __restrict__ Yt, const float* __restrict__ DK2,
                               const float* __restrict__ DQ2, bf16_t* __restrict__ SMT) {
    const int j = blockIdx.x, n = blockIdx.y, t = threadIdx.x;
    const int lane = t & 63, wave = t >> 6;
    const float* y = Yt + ((size_t)n * CD + j) * CD;
    const float* q2 = DQ2 + (size_t)n * CD;
    const float dk2 = DK2[(size_t)n * CD + j];
    const int i0 = t * 8;

    float v[8];
    float4 a = *(const float4*)(y + i0);
    float4 b = *(const float4*)(y + i0 + 4);
    float4 qa = *(const float4*)(q2 + i0);
    float4 qb = *(const float4*)(q2 + i0 + 4);
    v[0] = a.x * rsqrtf(fmaxf(dk2 * qa.x, 1e-12f));
    v[1] = a.y * rsqrtf(fmaxf(dk2 * qa.y, 1e-12f));
    v[2] = a.z * rsqrtf(fmaxf(dk2 * qa.z, 1e-12f));
    v[3] = a.w * rsqrtf(fmaxf(dk2 * qa.w, 1e-12f));
    v[4] = b.x * rsqrtf(fmaxf(dk2 * qb.x, 1e-12f));
    v[5] = b.y * rsqrtf(fmaxf(dk2 * qb.y, 1e-12f));
    v[6] = b.z * rsqrtf(fmaxf(dk2 * qb.z, 1e-12f));
    v[7] = b.w * rsqrtf(fmaxf(dk2 * qb.w, 1e-12f));

    float m = v[0];
#pragma unroll
    for (int e = 1; e < 8; ++e) m = fmaxf(m, v[e]);
#pragma unroll
    for (int off = 32; off; off >>= 1) m = fmaxf(m, __shfl_xor(m, off, 64));
    __shared__ float redm[4], reds[4];
    if (lane == 0) redm[wave] = m;
    __syncthreads();
    m = fmaxf(fmaxf(redm[0], redm[1]), fmaxf(redm[2], redm[3]));

    float e8[8];
    float s = 0.f;
#pragma unroll
    for (int e = 0; e < 8; ++e) { e8[e] = __expf(v[e] - m); s += e8[e]; }
#pragma unroll
    for (int off = 32; off; off >>= 1) s += __shfl_xor(s, off, 64);
    if (lane == 0) reds[wave] = s;
    __syncthreads();
    s = reds[0] + reds[1] + reds[2] + reds[3];
    const float inv = 1.f / s;

    bf16x8 o;
#pragma unroll
    for (int e = 0; e < 8; ++e) o[e] = (bf16_t)(e8[e] * inv);
    *(bf16x8*)(SMT + ((size_t)n * CD + j) * CD + i0) = o;
}

extern "C" void kernel_launch(void* const* d_in, const int* in_sizes, int n_in,
                              void* d_out, int out_size, void* d_ws, size_t ws_size,
                              hipStream_t stream) {
    const float* X   = (const float*)d_in[0];
    const float* Wk  = (const float*)d_in[1];
    const float* Wq  = (const float*)d_in[2];
    const float* Wk0 = (const float*)d_in[3];
    const float* Wq0 = (const float*)d_in[4];
    float* Z = (float*)d_out;

    const size_t NCB = (size_t)NB * CD * BD;   // 33,554,432
    const size_t CC  = (size_t)CD * CD;        //  4,194,304
    const size_t NCC = (size_t)NB * CC;

    char* p = (char*)d_ws;
    bf16_t* XbT = (bf16_t*)p; p += NCB * 2;            // 64 MiB  X^T bf16 [N,B,C]
    bf16_t* Wkb = (bf16_t*)p; p += CC * 2;             //  8 MiB
    bf16_t* Wqb = (bf16_t*)p; p += CC * 2;             //  8 MiB
    bf16_t* Kb  = (bf16_t*)p; p += NCB * 2;            // 64 MiB  K bf16 [N,C,B]
    bf16_t* Qb  = (bf16_t*)p; p += NCB * 2;            // 64 MiB
    float*  DK2 = (float*)p;  p += (size_t)NB * CD * 4;
    float*  DQ2 = (float*)p;  p += (size_t)NB * CD * 4;
    float*  Yt  = (float*)p;  p += NCC * 4;            // 128 MiB Y^T f32 [N,Cj,Ci]
    bf16_t* SMT = Kb;  // Kb is dead after Yt is computed; SMT bf16 [N,Cj,Ci] reuses it
    if ((size_t)(p - (char*)d_ws) > ws_size) return;

    dim3 blk(256);
    // 1) X -> XbT
    k_transpose_x<<<dim3(BD / 64, CD / 64, NB), blk, 0, stream>>>(X, XbT);
    // 2) W -> bf16
    k_convert_w<<<dim3(CC / 1024, 2), blk, 0, stream>>>(Wk, Wq, Wkb, Wqb);
    // 3) K = Wk*X + Wk0 ; Q = Wq*X + Wq0   (A=Wb [C,K=C], B=XbT [B,K=C])
    k_gemm_nt<1><<<dim3(16, 16, NB), blk, 0, stream>>>(Wkb, 0, XbT, (size_t)BD * CD, Kb, (size_t)CD * BD, Wk0);
    k_gemm_nt<1><<<dim3(16, 16, NB), blk, 0, stream>>>(Wqb, 0, XbT, (size_t)BD * CD, Qb, (size_t)CD * BD, Wq0);
    // 4) DK2/DQ2 row norms
    k_row_norm2<<<dim3(CD, NB, 2), blk, 0, stream>>>(Kb, Qb, DK2, DQ2);
    // 5) Yt[j,i] = sum_b K[j,b]*Q[i,b]   (A=Kb [C,K=B], B=Qb [C,K=B])
    k_gemm_nt<0><<<dim3(16, 16, NB), blk, 0, stream>>>(Kb, (size_t)CD * BD, Qb, (size_t)CD * BD, Yt, CC, nullptr);
    // 6) row softmax (over i) with cosine scale -> SMT bf16
    k_softmax_rows<<<dim3(CD, NB), blk, 0, stream>>>(Yt, DK2, DQ2, SMT);
    // 7) Z[j,b] = sum_i SMT[j,i]*X[i,b]  (A=SMT [C,K=C], B=XbT [B,K=C]) -> d_out f32
    k_gemm_nt<0><<<dim3(16, 16, NB), blk, 0, stream>>>(SMT, CC, XbT, (size_t)BD * CD, Z, (size_t)CD * BD, nullptr);
}

// Round 2
// 658.649 us; speedup vs baseline: 1.2075x; 1.2075x over previous
//
#include <hip/hip_runtime.h>
#include <hip/hip_bf16.h>

typedef __bf16 bf16_t;
typedef __bf16 bf16x8 __attribute__((ext_vector_type(8)));
typedef __bf16 bf16x4 __attribute__((ext_vector_type(4)));
typedef float  f32x4  __attribute__((ext_vector_type(4)));

#define NB 8
#define CD 2048
#define BD 2048
#define LD 2048
#define BK 64
#define NT (LD / BK)

#define BAR()    asm volatile("s_barrier" ::: "memory")
#define WAITL0() asm volatile("s_waitcnt lgkmcnt(0)" ::: "memory")
#define WAITV(n) asm volatile("s_waitcnt vmcnt(" #n ")" ::: "memory")

// ---------------- X [N,C,B] f32 -> XbT [N,B,C] bf16 (transpose + convert) ----------------
__global__ void k_transpose_x(const float* __restrict__ X, bf16_t* __restrict__ XbT) {
    __shared__ bf16_t tile[64][66];
    const int t = threadIdx.x;
    const int b0 = blockIdx.x * 64, c0 = blockIdx.y * 64, n = blockIdx.z;
    const float* Xn = X + (size_t)n * CD * BD;
    bf16_t* Tn = XbT + (size_t)n * BD * CD;
    const int cl = t & 63, rw = t >> 6;
#pragma unroll
    for (int r = 0; r < 16; ++r) {
        int row = r * 4 + rw;
        tile[row][cl] = (bf16_t)Xn[(size_t)(c0 + row) * BD + b0 + cl];
    }
    __syncthreads();
#pragma unroll
    for (int r = 0; r < 16; ++r) {
        int row = r * 4 + rw;
        Tn[(size_t)(b0 + row) * CD + c0 + cl] = tile[cl][row];
    }
}

// ---------------- Wk/Wq f32 -> bf16 ----------------
__global__ void k_convert_w(const float* __restrict__ Wk, const float* __restrict__ Wq,
                            bf16_t* __restrict__ Wkb, bf16_t* __restrict__ Wqb) {
    const size_t i = ((size_t)blockIdx.x * 256 + threadIdx.x) * 4;
    const float* src = blockIdx.y ? Wq : Wk;
    bf16_t* dst = blockIdx.y ? Wqb : Wkb;
    float4 v = *(const float4*)(src + i);
    bf16x4 o;
    o[0] = (bf16_t)v.x; o[1] = (bf16_t)v.y; o[2] = (bf16_t)v.z; o[3] = (bf16_t)v.w;
    *(bf16x4*)(dst + i) = o;
}

// ================= 256x256 8-phase NT GEMM =================
// C[M,N] = A[M,K](rm) * B[N,K](rm)^T, bf16 in, f32 acc. M=N=K=2048 per z-slice.
// 8 waves (2x4), BK=64, 128KiB LDS (2 dbuf x {A,B} x 2 halves [128][64]),
// G4 XOR swizzle (chunk ^= row&7) applied via pre-swizzled global_load_lds source,
// counted vmcnt(6/8) at phases 1/4 only, setprio around MFMA clusters.

__device__ __forceinline__ void gll16(const bf16_t* g, bf16_t* l) {
    __builtin_amdgcn_global_load_lds((const __attribute__((address_space(1))) void*)g,
                                     (__attribute__((address_space(3))) void*)l, 16, 0, 0);
}

// stage one 128x64 half: gsrc = element ptr at (row0, k0) of the half, row stride LD
__device__ __forceinline__ void stage_half(const bf16_t* gsrc, bf16_t* ldsh, int w, int l) {
    const int rr = l >> 3;                     // row within the wave's 8-row slice; == (r&7)
    const int ce = ((l & 7) ^ rr) * 8;         // pre-swizzled source chunk (involution)
#pragma unroll
    for (int i = 0; i < 2; ++i) {
        const bf16_t* g = gsrc + (size_t)(i * 64 + w * 8 + rr) * LD + ce;
        gll16(g, ldsh + i * 4096 + w * 512);   // wave-uniform dest; HW adds lane*16B
    }
}

// read one MFMA A/B fragment from a swizzled [128][64] half
__device__ __forceinline__ bf16x8 lds_frag(const bf16_t* hbase, int row16, int lr, int st, int ks, int swz) {
    const int r = row16 + lr;
    const int ce = (st * 32 + ks * 8) ^ swz;   // swz = (lr&7)<<3 == (r&7)<<3
    return *(const bf16x8*)(hbase + r * 64 + ce);
}

template <int EPI>  // 0: f32 store; 1: +bias[row], bf16 store
__global__ __launch_bounds__(512, 2) void k_gemm256(const bf16_t* __restrict__ Aall, size_t sA,
                                                    const bf16_t* __restrict__ Ball, size_t sB,
                                                    void* __restrict__ Call, size_t sC,
                                                    const float* __restrict__ bias) {
    __shared__ alignas(16) bf16_t Ah[2][2][128 * 64];  // [buf][half]
    __shared__ alignas(16) bf16_t Bh[2][2][128 * 64];
    const int tid = threadIdx.x;
    const int lane = tid & 63, wave = tid >> 6;
    const int wm = wave >> 2, wn = wave & 3;
    const int lr = lane & 15, ks = lane >> 4;
    const int swz = (lr & 7) << 3;

    // XCD-aware swizzle over 512 blocks (divisible by 8): each XCD owns one z-slice
    const int bid = blockIdx.x;
    const int lin = (bid & 7) * 64 + (bid >> 3);
    const int z = lin >> 6, rem = lin & 63, bm = rem >> 3, bn = rem & 7;
    const int m0 = bm * 256, n0 = bn * 256;

    const bf16_t* Ab = Aall + sA * z + (size_t)m0 * LD;
    const bf16_t* Bb = Ball + sB * z + (size_t)n0 * LD;

    // prologue: Ah0(0),Bh0(0),Ah1(0),Bh1(0),Ah0(1),Bh0(1) -> wait oldest 2 halves
    stage_half(Ab,                &Ah[0][0][0], wave, lane);
    stage_half(Bb,                &Bh[0][0][0], wave, lane);
    stage_half(Ab + 128 * LD,     &Ah[0][1][0], wave, lane);
    stage_half(Bb + 128 * LD,     &Bh[0][1][0], wave, lane);
    stage_half(Ab + BK,           &Ah[1][0][0], wave, lane);
    stage_half(Bb + BK,           &Bh[1][0][0], wave, lane);
    WAITV(8); BAR();

    f32x4 acc[8][4] = {};
    bf16x8 af[4][2], b0[2][2], b1[2][2];

    for (int t = 0; t < NT; ++t) {
        const int cur = t & 1, nxt = cur ^ 1;
        const int t1 = (t + 1 < NT) ? t + 1 : NT - 1;
        const int t2 = (t + 2 < NT) ? t + 2 : NT - 1;
        const bf16_t* A0c = &Ah[cur][0][0];
        const bf16_t* A1c = &Ah[cur][1][0];
        const bf16_t* B0c = &Bh[cur][0][0];
        const bf16_t* B1c = &Bh[cur][1][0];

        // ---- phase 1: quadrant (mh0, nh0); stage Ah1(t+1) ----
#pragma unroll
        for (int s = 0; s < 4; ++s)
#pragma unroll
            for (int st = 0; st < 2; ++st)
                af[s][st] = lds_frag(A0c, (s * 2 + wm) * 16, lr, st, ks, swz);
#pragma unroll
        for (int u = 0; u < 2; ++u)
#pragma unroll
            for (int st = 0; st < 2; ++st)
                b0[u][st] = lds_frag(B0c, (u * 4 + wn) * 16, lr, st, ks, swz);
        stage_half(Ab + 128 * LD + t1 * BK, &Ah[nxt][1][0], wave, lane);
        WAITV(6); BAR(); WAITL0();
        __builtin_amdgcn_s_setprio(1);
#pragma unroll
        for (int s = 0; s < 4; ++s)
#pragma unroll
            for (int u = 0; u < 2; ++u)
#pragma unroll
                for (int st = 0; st < 2; ++st)
                    acc[s][u] = __builtin_amdgcn_mfma_f32_16x16x32_bf16(af[s][st], b0[u][st], acc[s][u], 0, 0, 0);
        __builtin_amdgcn_s_setprio(0);
        BAR();

        // ---- phase 2: (mh0, nh1); stage Bh1(t+1) ----
#pragma unroll
        for (int u = 0; u < 2; ++u)
#pragma unroll
            for (int st = 0; st < 2; ++st)
                b1[u][st] = lds_frag(B1c, (u * 4 + wn) * 16, lr, st, ks, swz);
        stage_half(Bb + 128 * LD + t1 * BK, &Bh[nxt][1][0], wave, lane);
        BAR(); WAITL0();
        __builtin_amdgcn_s_setprio(1);
#pragma unroll
        for (int s = 0; s < 4; ++s)
#pragma unroll
            for (int u = 0; u < 2; ++u)
#pragma unroll
                for (int st = 0; st < 2; ++st)
                    acc[s][2 + u] = __builtin_amdgcn_mfma_f32_16x16x32_bf16(af[s][st], b1[u][st], acc[s][2 + u], 0, 0, 0);
        __builtin_amdgcn_s_setprio(0);
        BAR();

        // ---- phase 3: (mh1, nh0); stage Ah0(t+2) into cur (region dead since ph1) ----
#pragma unroll
        for (int s = 0; s < 4; ++s)
#pragma unroll
            for (int st = 0; st < 2; ++st)
                af[s][st] = lds_frag(A1c, (s * 2 + wm) * 16, lr, st, ks, swz);
        stage_half(Ab + t2 * BK, &Ah[cur][0][0], wave, lane);
        BAR(); WAITL0();
        __builtin_amdgcn_s_setprio(1);
#pragma unroll
        for (int s = 0; s < 4; ++s)
#pragma unroll
            for (int u = 0; u < 2; ++u)
#pragma unroll
                for (int st = 0; st < 2; ++st)
                    acc[4 + s][u] = __builtin_amdgcn_mfma_f32_16x16x32_bf16(af[s][st], b0[u][st], acc[4 + s][u], 0, 0, 0);
        __builtin_amdgcn_s_setprio(0);
        BAR();

        // ---- phase 4: (mh1, nh1); stage Bh0(t+2); counted wait for next tile's k0 halves ----
        stage_half(Bb + t2 * BK, &Bh[cur][0][0], wave, lane);
        WAITV(8); BAR();
        __builtin_amdgcn_s_setprio(1);
#pragma unroll
        for (int s = 0; s < 4; ++s)
#pragma unroll
            for (int u = 0; u < 2; ++u)
#pragma unroll
                for (int st = 0; st < 2; ++st)
                    acc[4 + s][2 + u] = __builtin_amdgcn_mfma_f32_16x16x32_bf16(af[s][st], b1[u][st], acc[4 + s][2 + u], 0, 0, 0);
        __builtin_amdgcn_s_setprio(0);
        BAR();
    }
    WAITV(0);  // drain dummy tail prefetches before any wave can exit

    // epilogue: D row = ks*4+j (A side), col = lr (B side)
    const int rsub = ks * 4;
#pragma unroll
    for (int f = 0; f < 8; ++f) {
        const int h = f >> 2, s = f & 3;
        const int rb = m0 + h * 128 + (s * 2 + wm) * 16 + rsub;
#pragma unroll
        for (int j = 0; j < 4; ++j) {
            const int r = rb + j;
            float bv = 0.f;
            if (EPI == 1) bv = bias[r];
#pragma unroll
            for (int g = 0; g < 4; ++g) {
                const int c = n0 + (g >> 1) * 128 + ((g & 1) * 4 + wn) * 16 + lr;
                const float v = acc[f][g][j] + bv;
                if (EPI == 1) ((bf16_t*)Call)[sC * z + (size_t)r * LD + c] = (bf16_t)v;
                else          ((float*)Call)[sC * z + (size_t)r * LD + c] = v;
            }
        }
    }
}

// ---------------- squared row norms of Kb/Qb (bf16 [N,C,B]) -> f32 [N,C] ----------------
__global__ void k_row_norm2(const bf16_t* __restrict__ Kb, const bf16_t* __restrict__ Qb,
                            float* __restrict__ DK2, float* __restrict__ DQ2) {
    const int row = blockIdx.x, n = blockIdx.y;
    const bf16_t* src = blockIdx.z ? Qb : Kb;
    float* dst = blockIdx.z ? DQ2 : DK2;
    const bf16_t* pr = src + ((size_t)n * CD + row) * BD + threadIdx.x * 8;
    bf16x8 v = *(const bf16x8*)pr;
    float s = 0.f;
#pragma unroll
    for (int e = 0; e < 8; ++e) { float x = (float)v[e]; s += x * x; }
#pragma unroll
    for (int off = 32; off; off >>= 1) s += __shfl_xor(s, off, 64);
    __shared__ float ws[4];
    if ((threadIdx.x & 63) == 0) ws[threadIdx.x >> 6] = s;
    __syncthreads();
    if (threadIdx.x == 0) dst[(size_t)n * CD + row] = ws[0] + ws[1] + ws[2] + ws[3];
}

// ------- per-row: scale by rsqrt(DQ2[i]*DK2[j]), softmax over i, write bf16 SMT[j,i] -------
__global__ void k_softmax_rows(const float* __restrict__ Yt, const float* __restrict__ DK2,
                               const float* __restrict__ DQ2, bf16_t* __restrict__ SMT) {
    const int j = blockIdx.x, n = blockIdx.y, t = threadIdx.x;
    const int lane = t & 63, wave = t >> 6;
    const float* y = Yt + ((size_t)n * CD + j) * CD;
    const float* q2 = DQ2 + (size_t)n * CD;
    const float dk2 = DK2[(size_t)n * CD + j];
    const int i0 = t * 8;

    float v[8];
    float4 a = *(const float4*)(y + i0);
    float4 b = *(const float4*)(y + i0 + 4);
    float4 qa = *(const float4*)(q2 + i0);
    float4 qb = *(const float4*)(q2 + i0 + 4);
    v[0] = a.x * rsqrtf(fmaxf(dk2 * qa.x, 1e-12f));
    v[1] = a.y * rsqrtf(fmaxf(dk2 * qa.y, 1e-12f));
    v[2] = a.z * rsqrtf(fmaxf(dk2 * qa.z, 1e-12f));
    v[3] = a.w * rsqrtf(fmaxf(dk2 * qa.w, 1e-12f));
    v[4] = b.x * rsqrtf(fmaxf(dk2 * qb.x, 1e-12f));
    v[5] = b.y * rsqrtf(fmaxf(dk2 * qb.y, 1e-12f));
    v[6] = b.z * rsqrtf(fmaxf(dk2 * qb.z, 1e-12f));
    v[7] = b.w * rsqrtf(fmaxf(dk2 * qb.w, 1e-12f));

    float m = v[0];
#pragma unroll
    for (int e = 1; e < 8; ++e) m = fmaxf(m, v[e]);
#pragma unroll
    for (int off = 32; off; off >>= 1) m = fmaxf(m, __shfl_xor(m, off, 64));
    __shared__ float redm[4], reds[4];
    if (lane == 0) redm[wave] = m;
    __syncthreads();
    m = fmaxf(fmaxf(redm[0], redm[1]), fmaxf(redm[2], redm[3]));

    float e8[8];
    float s = 0.f;
#pragma unroll
    for (int e = 0; e < 8; ++e) { e8[e] = __expf(v[e] - m); s += e8[e]; }
#pragma unroll
    for (int off = 32; off; off >>= 1) s += __shfl_xor(s, off, 64);
    if (lane == 0) reds[wave] = s;
    __syncthreads();
    s = reds[0] + reds[1] + reds[2] + reds[3];
    const float inv = 1.f / s;

    bf16x8 o;
#pragma unroll
    for (int e = 0; e < 8; ++e) o[e] = (bf16_t)(e8[e] * inv);
    *(bf16x8*)(SMT + ((size_t)n * CD + j) * CD + i0) = o;
}

extern "C" void kernel_launch(void* const* d_in, const int* in_sizes, int n_in,
                              void* d_out, int out_size, void* d_ws, size_t ws_size,
                              hipStream_t stream) {
    const float* X   = (const float*)d_in[0];
    const float* Wk  = (const float*)d_in[1];
    const float* Wq  = (const float*)d_in[2];
    const float* Wk0 = (const float*)d_in[3];
    const float* Wq0 = (const float*)d_in[4];
    float* Z = (float*)d_out;

    const size_t NCB = (size_t)NB * CD * BD;
    const size_t CC  = (size_t)CD * CD;
    const size_t NCC = (size_t)NB * CC;

    char* p = (char*)d_ws;
    bf16_t* XbT = (bf16_t*)p; p += NCB * 2;
    bf16_t* Wkb = (bf16_t*)p; p += CC * 2;
    bf16_t* Wqb = (bf16_t*)p; p += CC * 2;
    bf16_t* Kb  = (bf16_t*)p; p += NCB * 2;
    bf16_t* Qb  = (bf16_t*)p; p += NCB * 2;
    float*  DK2 = (float*)p;  p += (size_t)NB * CD * 4;
    float*  DQ2 = (float*)p;  p += (size_t)NB * CD * 4;
    float*  Yt  = (float*)p;  p += NCC * 4;
    bf16_t* SMT = Kb;  // Kb dead after Yt; reuse
    if ((size_t)(p - (char*)d_ws) > ws_size) return;

    dim3 blk(256);
    k_transpose_x<<<dim3(BD / 64, CD / 64, NB), blk, 0, stream>>>(X, XbT);
    k_convert_w<<<dim3(CC / 1024, 2), blk, 0, stream>>>(Wk, Wq, Wkb, Wqb);
    // K = Wk*X + Wk0 ; Q = Wq*X + Wq0
    k_gemm256<1><<<512, 512, 0, stream>>>(Wkb, 0, XbT, (size_t)BD * CD, Kb, (size_t)CD * BD, Wk0);
    k_gemm256<1><<<512, 512, 0, stream>>>(Wqb, 0, XbT, (size_t)BD * CD, Qb, (size_t)CD * BD, Wq0);
    k_row_norm2<<<dim3(CD, NB, 2), blk, 0, stream>>>(Kb, Qb, DK2, DQ2);
    // Yt[j,i] = sum_b K[j,b]*Q[i,b]
    k_gemm256<0><<<512, 512, 0, stream>>>(Kb, (size_t)CD * BD, Qb, (size_t)CD * BD, Yt, CC, nullptr);
    k_softmax_rows<<<dim3(CD, NB), blk, 0, stream>>>(Yt, DK2, DQ2, SMT);
    // Z[j,b] = sum_i SMT[j,i]*X[i,b]
    k_gemm256<0><<<512, 512, 0, stream>>>(SMT, CC, XbT, (size_t)BD * CD, Z, (size_t)CD * BD, nullptr);
}

// Round 3
// 627.026 us; speedup vs baseline: 1.2684x; 1.0504x over previous
//
#include <hip/hip_runtime.h>
#include <hip/hip_bf16.h>

typedef __bf16 bf16_t;
typedef __bf16 bf16x8 __attribute__((ext_vector_type(8)));
typedef __bf16 bf16x4 __attribute__((ext_vector_type(4)));
typedef float  f32x4  __attribute__((ext_vector_type(4)));

#define NB 8
#define CD 2048
#define BD 2048
#define LD 2048
#define BK 64
#define NT (LD / BK)

#define BAR()    asm volatile("s_barrier" ::: "memory")
#define WAITV(n) asm volatile("s_waitcnt vmcnt(" #n ")" ::: "memory")

// ---------------- X [N,C,B] f32 -> XbT [N,B,C] bf16 (transpose + convert) ----------------
__global__ void k_transpose_x(const float* __restrict__ X, bf16_t* __restrict__ XbT) {
    __shared__ bf16_t tile[64][66];
    const int t = threadIdx.x;
    const int b0 = blockIdx.x * 64, c0 = blockIdx.y * 64, n = blockIdx.z;
    const float* Xn = X + (size_t)n * CD * BD;
    bf16_t* Tn = XbT + (size_t)n * BD * CD;
    const int cl = t & 63, rw = t >> 6;
#pragma unroll
    for (int r = 0; r < 16; ++r) {
        int row = r * 4 + rw;
        tile[row][cl] = (bf16_t)Xn[(size_t)(c0 + row) * BD + b0 + cl];
    }
    __syncthreads();
#pragma unroll
    for (int r = 0; r < 16; ++r) {
        int row = r * 4 + rw;
        Tn[(size_t)(b0 + row) * CD + c0 + cl] = tile[cl][row];
    }
}

// ---------------- Wk/Wq f32 -> bf16 ----------------
__global__ void k_convert_w(const float* __restrict__ Wk, const float* __restrict__ Wq,
                            bf16_t* __restrict__ Wkb, bf16_t* __restrict__ Wqb) {
    const size_t i = ((size_t)blockIdx.x * 256 + threadIdx.x) * 4;
    const float* src = blockIdx.y ? Wq : Wk;
    bf16_t* dst = blockIdx.y ? Wqb : Wkb;
    float4 v = *(const float4*)(src + i);
    bf16x4 o;
    o[0] = (bf16_t)v.x; o[1] = (bf16_t)v.y; o[2] = (bf16_t)v.z; o[3] = (bf16_t)v.w;
    *(bf16x4*)(dst + i) = o;
}

// ================= 256x256 NT GEMM, 4 phases/K-tile with cross-phase frag read-ahead ======
// C[M,N] = A[M,K](rm) * B[N,K](rm)^T. 8 waves (2Mx4N), BK=64, 128KiB LDS,
// XOR swizzle via pre-swizzled global_load_lds source, counted vmcnt (never 0 in-loop),
// ds_reads issued one phase ahead of their MFMA so LDS delivery overlaps prior MFMA cluster.

__device__ __forceinline__ void gll16(const bf16_t* g, bf16_t* l) {
    __builtin_amdgcn_global_load_lds((const __attribute__((address_space(1))) void*)g,
                                     (__attribute__((address_space(3))) void*)l, 16, 0, 0);
}

__device__ __forceinline__ void stage_half(const bf16_t* gsrc, bf16_t* ldsh, int w, int l) {
    const int rr = l >> 3;
    const int ce = ((l & 7) ^ rr) * 8;  // pre-swizzled source chunk (involution)
#pragma unroll
    for (int i = 0; i < 2; ++i) {
        const bf16_t* g = gsrc + (size_t)(i * 64 + w * 8 + rr) * LD + ce;
        gll16(g, ldsh + i * 4096 + w * 512);
    }
}

__device__ __forceinline__ bf16x8 lds_frag(const bf16_t* hbase, int row16, int lr, int st, int ks, int swz) {
    const int r = row16 + lr;
    const int ce = (st * 32 + ks * 8) ^ swz;
    return *(const bf16x8*)(hbase + r * 64 + ce);
}

template <int EPI>  // 0: f32 store; 1: +bias[row], bf16 store
__global__ __launch_bounds__(512, 2) void k_gemm256(const bf16_t* __restrict__ Aall, size_t sA,
                                                    const bf16_t* __restrict__ Ball, size_t sB,
                                                    void* __restrict__ Call, size_t sC,
                                                    const float* __restrict__ bias) {
    __shared__ alignas(16) bf16_t Ah[2][2][128 * 64];  // [buf][half]
    __shared__ alignas(16) bf16_t Bh[2][2][128 * 64];
    const int tid = threadIdx.x;
    const int lane = tid & 63, wave = tid >> 6;
    const int wm = wave >> 2, wn = wave & 3;
    const int lr = lane & 15, ks = lane >> 4;
    const int swz = (lr & 7) << 3;

    const int bid = blockIdx.x;
    const int lin = (bid & 7) * 64 + (bid >> 3);   // XCD-aware remap (512 % 8 == 0: bijective)
    const int z = lin >> 6, rem = lin & 63, bm = rem >> 3, bn = rem & 7;
    const int m0 = bm * 256, n0 = bn * 256;

    const bf16_t* Ab = Aall + sA * z + (size_t)m0 * LD;
    const bf16_t* Bb = Ball + sB * z + (size_t)n0 * LD;

    // prologue: A0(0),B0(0),A1(0),B1(0),A0(1),B0(1)  (12 loads)
    stage_half(Ab,            &Ah[0][0][0], wave, lane);
    stage_half(Bb,            &Bh[0][0][0], wave, lane);
    stage_half(Ab + 128 * LD, &Ah[0][1][0], wave, lane);
    stage_half(Bb + 128 * LD, &Bh[0][1][0], wave, lane);
    stage_half(Ab + BK,       &Ah[1][0][0], wave, lane);
    stage_half(Bb + BK,       &Bh[1][0][0], wave, lane);
    WAITV(8);  // A0(0), B0(0) resident
    BAR();

    f32x4 acc[8][4] = {};
    bf16x8 fA0[4][2], fA1[4][2], fB0[2][2], fB1[2][2];

    // preload tile-0 A0/B0 fragments (consumed by P1's MFMA; compiler inserts lgkm waits)
#pragma unroll
    for (int s = 0; s < 4; ++s)
#pragma unroll
        for (int st = 0; st < 2; ++st)
            fA0[s][st] = lds_frag(&Ah[0][0][0], (s * 2 + wm) * 16, lr, st, ks, swz);
#pragma unroll
    for (int u = 0; u < 2; ++u)
#pragma unroll
        for (int st = 0; st < 2; ++st)
            fB0[u][st] = lds_frag(&Bh[0][0][0], (u * 4 + wn) * 16, lr, st, ks, swz);

    for (int t = 0; t < NT; ++t) {
        const int cur = t & 1, nxt = cur ^ 1;
        const int t1 = (t + 1 < NT) ? t + 1 : NT - 1;
        const int t2 = (t + 2 < NT) ? t + 2 : NT - 1;
        const bf16_t* A1c = &Ah[cur][1][0];
        const bf16_t* B1c = &Bh[cur][1][0];
        const bf16_t* A0n = &Ah[nxt][0][0];
        const bf16_t* B0n = &Bh[nxt][0][0];

        // ---- P1: read B1(t); stage A1(t+1); MFMA A0xB0 ----
        BAR();
        WAITV(4);  // retire stages through B1(t)
#pragma unroll
        for (int u = 0; u < 2; ++u)
#pragma unroll
            for (int st = 0; st < 2; ++st)
                fB1[u][st] = lds_frag(B1c, (u * 4 + wn) * 16, lr, st, ks, swz);
        stage_half(Ab + 128 * LD + t1 * BK, &Ah[nxt][1][0], wave, lane);
        __builtin_amdgcn_s_setprio(1);
#pragma unroll
        for (int s = 0; s < 4; ++s)
#pragma unroll
            for (int u = 0; u < 2; ++u)
#pragma unroll
                for (int st = 0; st < 2; ++st)
                    acc[s][u] = __builtin_amdgcn_mfma_f32_16x16x32_bf16(fA0[s][st], fB0[u][st], acc[s][u], 0, 0, 0);
        __builtin_amdgcn_s_setprio(0);

        // ---- P2: read A1(t); stage B1(t+1); MFMA A0xB1 ----
        BAR();
#pragma unroll
        for (int s = 0; s < 4; ++s)
#pragma unroll
            for (int st = 0; st < 2; ++st)
                fA1[s][st] = lds_frag(A1c, (s * 2 + wm) * 16, lr, st, ks, swz);
        stage_half(Bb + 128 * LD + t1 * BK, &Bh[nxt][1][0], wave, lane);
        __builtin_amdgcn_s_setprio(1);
#pragma unroll
        for (int s = 0; s < 4; ++s)
#pragma unroll
            for (int u = 0; u < 2; ++u)
#pragma unroll
                for (int st = 0; st < 2; ++st)
                    acc[s][2 + u] = __builtin_amdgcn_mfma_f32_16x16x32_bf16(fA0[s][st], fB1[u][st], acc[s][2 + u], 0, 0, 0);
        __builtin_amdgcn_s_setprio(0);

        // ---- P3: read A0(t+1); stage A0(t+2); MFMA A1xB0 ----
        BAR();
        WAITV(6);  // retire A0(t+1) stage
#pragma unroll
        for (int s = 0; s < 4; ++s)
#pragma unroll
            for (int st = 0; st < 2; ++st)
                fA0[s][st] = lds_frag(A0n, (s * 2 + wm) * 16, lr, st, ks, swz);
        stage_half(Ab + t2 * BK, &Ah[cur][0][0], wave, lane);
        __builtin_amdgcn_s_setprio(1);
#pragma unroll
        for (int s = 0; s < 4; ++s)
#pragma unroll
            for (int u = 0; u < 2; ++u)
#pragma unroll
                for (int st = 0; st < 2; ++st)
                    acc[4 + s][u] = __builtin_amdgcn_mfma_f32_16x16x32_bf16(fA1[s][st], fB0[u][st], acc[4 + s][u], 0, 0, 0);
        __builtin_amdgcn_s_setprio(0);

        // ---- P4: read B0(t+1); stage B0(t+2); MFMA A1xB1 ----
        BAR();
        WAITV(6);  // retire B0(t+1) stage
#pragma unroll
        for (int u = 0; u < 2; ++u)
#pragma unroll
            for (int st = 0; st < 2; ++st)
                fB0[u][st] = lds_frag(B0n, (u * 4 + wn) * 16, lr, st, ks, swz);
        stage_half(Bb + t2 * BK, &Bh[cur][0][0], wave, lane);
        __builtin_amdgcn_s_setprio(1);
#pragma unroll
        for (int s = 0; s < 4; ++s)
#pragma unroll
            for (int u = 0; u < 2; ++u)
#pragma unroll
                for (int st = 0; st < 2; ++st)
                    acc[4 + s][2 + u] = __builtin_amdgcn_mfma_f32_16x16x32_bf16(fA1[s][st], fB1[u][st], acc[4 + s][2 + u], 0, 0, 0);
        __builtin_amdgcn_s_setprio(0);
    }
    WAITV(0);  // drain tail dummy stages before exit/epilogue

    const int rsub = ks * 4;
#pragma unroll
    for (int f = 0; f < 8; ++f) {
        const int h = f >> 2, s = f & 3;
        const int rb = m0 + h * 128 + (s * 2 + wm) * 16 + rsub;
#pragma unroll
        for (int j = 0; j < 4; ++j) {
            const int r = rb + j;
            float bv = 0.f;
            if (EPI == 1) bv = bias[r];
#pragma unroll
            for (int g = 0; g < 4; ++g) {
                const int c = n0 + (g >> 1) * 128 + ((g & 1) * 4 + wn) * 16 + lr;
                const float v = acc[f][g][j] + bv;
                if (EPI == 1) ((bf16_t*)Call)[sC * z + (size_t)r * LD + c] = (bf16_t)v;
                else          ((float*)Call)[sC * z + (size_t)r * LD + c] = v;
            }
        }
    }
}

// ---------------- squared row norms of Kb/Qb (bf16 [N,C,B]) -> f32 [N,C] ----------------
__global__ void k_row_norm2(const bf16_t* __restrict__ Kb, const bf16_t* __restrict__ Qb,
                            float* __restrict__ DK2, float* __restrict__ DQ2) {
    const int row = blockIdx.x, n = blockIdx.y;
    const bf16_t* src = blockIdx.z ? Qb : Kb;
    float* dst = blockIdx.z ? DQ2 : DK2;
    const bf16_t* pr = src + ((size_t)n * CD + row) * BD + threadIdx.x * 8;
    bf16x8 v = *(const bf16x8*)pr;
    float s = 0.f;
#pragma unroll
    for (int e = 0; e < 8; ++e) { float x = (float)v[e]; s += x * x; }
#pragma unroll
    for (int off = 32; off; off >>= 1) s += __shfl_xor(s, off, 64);
    __shared__ float ws[4];
    if ((threadIdx.x & 63) == 0) ws[threadIdx.x >> 6] = s;
    __syncthreads();
    if (threadIdx.x == 0) dst[(size_t)n * CD + row] = ws[0] + ws[1] + ws[2] + ws[3];
}

// ------- per-row: scale by rsqrt(DQ2[i]*DK2[j]), softmax over i, write bf16 SMT[j,i] -------
__global__ void k_softmax_rows(const float* __restrict__ Yt, const float* __restrict__ DK2,
                               const float* __restrict__ DQ2, bf16_t* __restrict__ SMT) {
    const int j = blockIdx.x, n = blockIdx.y, t = threadIdx.x;
    const int lane = t & 63, wave = t >> 6;
    const float* y = Yt + ((size_t)n * CD + j) * CD;
    const float* q2 = DQ2 + (size_t)n * CD;
    const float dk2 = DK2[(size_t)n * CD + j];
    const int i0 = t * 8;

    float v[8];
    float4 a = *(const float4*)(y + i0);
    float4 b = *(const float4*)(y + i0 + 4);
    float4 qa = *(const float4*)(q2 + i0);
    float4 qb = *(const float4*)(q2 + i0 + 4);
    v[0] = a.x * rsqrtf(fmaxf(dk2 * qa.x, 1e-12f));
    v[1] = a.y * rsqrtf(fmaxf(dk2 * qa.y, 1e-12f));
    v[2] = a.z * rsqrtf(fmaxf(dk2 * qa.z, 1e-12f));
    v[3] = a.w * rsqrtf(fmaxf(dk2 * qa.w, 1e-12f));
    v[4] = b.x * rsqrtf(fmaxf(dk2 * qb.x, 1e-12f));
    v[5] = b.y * rsqrtf(fmaxf(dk2 * qb.y, 1e-12f));
    v[6] = b.z * rsqrtf(fmaxf(dk2 * qb.z, 1e-12f));
    v[7] = b.w * rsqrtf(fmaxf(dk2 * qb.w, 1e-12f));

    float m = v[0];
#pragma unroll
    for (int e = 1; e < 8; ++e) m = fmaxf(m, v[e]);
#pragma unroll
    for (int off = 32; off; off >>= 1) m = fmaxf(m, __shfl_xor(m, off, 64));
    __shared__ float redm[4], reds[4];
    if (lane == 0) redm[wave] = m;
    __syncthreads();
    m = fmaxf(fmaxf(redm[0], redm[1]), fmaxf(redm[2], redm[3]));

    float e8[8];
    float s = 0.f;
#pragma unroll
    for (int e = 0; e < 8; ++e) { e8[e] = __expf(v[e] - m); s += e8[e]; }
#pragma unroll
    for (int off = 32; off; off >>= 1) s += __shfl_xor(s, off, 64);
    if (lane == 0) reds[wave] = s;
    __syncthreads();
    s = reds[0] + reds[1] + reds[2] + reds[3];
    const float inv = 1.f / s;

    bf16x8 o;
#pragma unroll
    for (int e = 0; e < 8; ++e) o[e] = (bf16_t)(e8[e] * inv);
    *(bf16x8*)(SMT + ((size_t)n * CD + j) * CD + i0) = o;
}

extern "C" void kernel_launch(void* const* d_in, const int* in_sizes, int n_in,
                              void* d_out, int out_size, void* d_ws, size_t ws_size,
                              hipStream_t stream) {
    const float* X   = (const float*)d_in[0];
    const float* Wk  = (const float*)d_in[1];
    const float* Wq  = (const float*)d_in[2];
    const float* Wk0 = (const float*)d_in[3];
    const float* Wq0 = (const float*)d_in[4];
    float* Z = (float*)d_out;

    const size_t NCB = (size_t)NB * CD * BD;
    const size_t CC  = (size_t)CD * CD;
    const size_t NCC = (size_t)NB * CC;

    char* p = (char*)d_ws;
    bf16_t* XbT = (bf16_t*)p; p += NCB * 2;
    bf16_t* Wkb = (bf16_t*)p; p += CC * 2;
    bf16_t* Wqb = (bf16_t*)p; p += CC * 2;
    bf16_t* Kb  = (bf16_t*)p; p += NCB * 2;
    bf16_t* Qb  = (bf16_t*)p; p += NCB * 2;
    float*  DK2 = (float*)p;  p += (size_t)NB * CD * 4;
    float*  DQ2 = (float*)p;  p += (size_t)NB * CD * 4;
    float*  Yt  = (float*)p;  p += NCC * 4;
    bf16_t* SMT = Kb;  // Kb dead after Yt; reuse
    if ((size_t)(p - (char*)d_ws) > ws_size) return;

    dim3 blk(256);
    k_transpose_x<<<dim3(BD / 64, CD / 64, NB), blk, 0, stream>>>(X, XbT);
    k_convert_w<<<dim3(CC / 1024, 2), blk, 0, stream>>>(Wk, Wq, Wkb, Wqb);
    k_gemm256<1><<<512, 512, 0, stream>>>(Wkb, 0, XbT, (size_t)BD * CD, Kb, (size_t)CD * BD, Wk0);
    k_gemm256<1><<<512, 512, 0, stream>>>(Wqb, 0, XbT, (size_t)BD * CD, Qb, (size_t)CD * BD, Wq0);
    k_row_norm2<<<dim3(CD, NB, 2), blk, 0, stream>>>(Kb, Qb, DK2, DQ2);
    k_gemm256<0><<<512, 512, 0, stream>>>(Kb, (size_t)CD * BD, Qb, (size_t)CD * BD, Yt, CC, nullptr);
    k_softmax_rows<<<dim3(CD, NB), blk, 0, stream>>>(Yt, DK2, DQ2, SMT);
    k_gemm256<0><<<512, 512, 0, stream>>>(SMT, CC, XbT, (size_t)BD * CD, Z, (size_t)CD * BD, nullptr);
}

// Round 4
// 604.023 us; speedup vs baseline: 1.3167x; 1.0381x over previous
//
#include <hip/hip_runtime.h>
#include <hip/hip_bf16.h>

typedef __bf16 bf16_t;
typedef __bf16 bf16x8 __attribute__((ext_vector_type(8)));
typedef __bf16 bf16x4 __attribute__((ext_vector_type(4)));
typedef float  f32x4  __attribute__((ext_vector_type(4)));

#define NB 8
#define CD 2048
#define BD 2048
#define LD 2048
#define BK 64
#define NT (LD / BK)

#define BAR()    asm volatile("s_barrier" ::: "memory")
#define WAITV(n) asm volatile("s_waitcnt vmcnt(" #n ")" ::: "memory")

// ---------------- X [N,C,B] f32 -> XbT [N,B,C] bf16 (transpose + convert) ----------------
__global__ void k_transpose_x(const float* __restrict__ X, bf16_t* __restrict__ XbT) {
    __shared__ bf16_t tile[64][66];
    const int t = threadIdx.x;
    const int b0 = blockIdx.x * 64, c0 = blockIdx.y * 64, n = blockIdx.z;
    const float* Xn = X + (size_t)n * CD * BD;
    bf16_t* Tn = XbT + (size_t)n * BD * CD;
    const int cl = t & 63, rw = t >> 6;
#pragma unroll
    for (int r = 0; r < 16; ++r) {
        int row = r * 4 + rw;
        tile[row][cl] = (bf16_t)Xn[(size_t)(c0 + row) * BD + b0 + cl];
    }
    __syncthreads();
#pragma unroll
    for (int r = 0; r < 16; ++r) {
        int row = r * 4 + rw;
        Tn[(size_t)(b0 + row) * CD + c0 + cl] = tile[cl][row];
    }
}

// ---------------- Wk/Wq f32 -> bf16 ----------------
__global__ void k_convert_w(const float* __restrict__ Wk, const float* __restrict__ Wq,
                            bf16_t* __restrict__ Wkb, bf16_t* __restrict__ Wqb) {
    const size_t i = ((size_t)blockIdx.x * 256 + threadIdx.x) * 4;
    const float* src = blockIdx.y ? Wq : Wk;
    bf16_t* dst = blockIdx.y ? Wqb : Wkb;
    float4 v = *(const float4*)(src + i);
    bf16x4 o;
    o[0] = (bf16_t)v.x; o[1] = (bf16_t)v.y; o[2] = (bf16_t)v.z; o[3] = (bf16_t)v.w;
    *(bf16x4*)(dst + i) = o;
}

// ================= 256x256 NT GEMM, 4 phases/K-tile, uniform 4-phase stage slack ==========
// C[M,N] = A[M,K](rm) * B[N,K](rm)^T. 8 waves (2Mx4N), BK=64, 128KiB LDS.
// ds_reads issued one phase ahead of their MFMA; ALL gll stages get >=4-phase deadline:
// P1 stages A1&B1(t+1) (vmcnt(4)), P2 stages nothing (no wait), P3/P4 stage A0/B0(t+2)
// (vmcnt(6) each). Steady state: 8 loads in flight at every phase entry; each wait
// retires exactly the half that phase reads, issued ~1400+ cyc earlier (> HBM latency).

__device__ __forceinline__ void gll16(const bf16_t* g, bf16_t* l) {
    __builtin_amdgcn_global_load_lds((const __attribute__((address_space(1))) void*)g,
                                     (__attribute__((address_space(3))) void*)l, 16, 0, 0);
}

__device__ __forceinline__ void stage_half(const bf16_t* gsrc, bf16_t* ldsh, int w, int l) {
    const int rr = l >> 3;
    const int ce = ((l & 7) ^ rr) * 8;  // pre-swizzled source chunk (involution)
#pragma unroll
    for (int i = 0; i < 2; ++i) {
        const bf16_t* g = gsrc + (size_t)(i * 64 + w * 8 + rr) * LD + ce;
        gll16(g, ldsh + i * 4096 + w * 512);
    }
}

__device__ __forceinline__ bf16x8 lds_frag(const bf16_t* hbase, int row16, int lr, int st, int ks, int swz) {
    const int r = row16 + lr;
    const int ce = (st * 32 + ks * 8) ^ swz;
    return *(const bf16x8*)(hbase + r * 64 + ce);
}

template <int EPI>  // 0: f32 store; 1: +bias[row], bf16 store
__global__ __launch_bounds__(512, 2) void k_gemm256(const bf16_t* __restrict__ Aall, size_t sA,
                                                    const bf16_t* __restrict__ Ball, size_t sB,
                                                    void* __restrict__ Call, size_t sC,
                                                    const float* __restrict__ bias) {
    __shared__ alignas(16) bf16_t Ah[2][2][128 * 64];  // [buf][half]
    __shared__ alignas(16) bf16_t Bh[2][2][128 * 64];
    const int tid = threadIdx.x;
    const int lane = tid & 63, wave = tid >> 6;
    const int wm = wave >> 2, wn = wave & 3;
    const int lr = lane & 15, ks = lane >> 4;
    const int swz = (lr & 7) << 3;

    const int bid = blockIdx.x;
    const int lin = (bid & 7) * 64 + (bid >> 3);   // XCD-aware remap (512 % 8 == 0: bijective)
    const int z = lin >> 6, rem = lin & 63, bm = rem >> 3, bn = rem & 7;
    const int m0 = bm * 256, n0 = bn * 256;

    const bf16_t* Ab = Aall + sA * z + (size_t)m0 * LD;
    const bf16_t* Bb = Ball + sB * z + (size_t)n0 * LD;

    // prologue stages (12 loads): A0(0),B0(0),A1(0),B1(0),A0(1),B0(1)
    stage_half(Ab,            &Ah[0][0][0], wave, lane);
    stage_half(Bb,            &Bh[0][0][0], wave, lane);
    stage_half(Ab + 128 * LD, &Ah[0][1][0], wave, lane);
    stage_half(Bb + 128 * LD, &Bh[0][1][0], wave, lane);
    stage_half(Ab + BK,       &Ah[1][0][0], wave, lane);
    stage_half(Bb + BK,       &Bh[1][0][0], wave, lane);
    WAITV(8);  // A0(0), B0(0) resident
    BAR();

    f32x4 acc[8][4] = {};
    bf16x8 fA0[4][2], fA1[4][2], fB0[2][2], fB1[2][2];

    // preload tile-0 A0/B0 fragments (consumed by P1's MFMA)
#pragma unroll
    for (int s = 0; s < 4; ++s)
#pragma unroll
        for (int st = 0; st < 2; ++st)
            fA0[s][st] = lds_frag(&Ah[0][0][0], (s * 2 + wm) * 16, lr, st, ks, swz);
#pragma unroll
    for (int u = 0; u < 2; ++u)
#pragma unroll
        for (int st = 0; st < 2; ++st)
            fB0[u][st] = lds_frag(&Bh[0][0][0], (u * 4 + wn) * 16, lr, st, ks, swz);

    for (int t = 0; t < NT; ++t) {
        const int cur = t & 1, nxt = cur ^ 1;
        const int t1 = (t + 1 < NT) ? t + 1 : NT - 1;
        const int t2 = (t + 2 < NT) ? t + 2 : NT - 1;
        const bf16_t* A1c = &Ah[cur][1][0];
        const bf16_t* B1c = &Bh[cur][1][0];
        const bf16_t* A0n = &Ah[nxt][0][0];
        const bf16_t* B0n = &Bh[nxt][0][0];

        // ---- P1: read B1(t); stage A1(t+1)+B1(t+1); MFMA A0xB0 ----
        BAR();
        WAITV(4);  // retires A1(t), B1(t) (staged 4-5 phases ago)
#pragma unroll
        for (int u = 0; u < 2; ++u)
#pragma unroll
            for (int st = 0; st < 2; ++st)
                fB1[u][st] = lds_frag(B1c, (u * 4 + wn) * 16, lr, st, ks, swz);
        stage_half(Ab + 128 * LD + t1 * BK, &Ah[nxt][1][0], wave, lane);
        stage_half(Bb + 128 * LD + t1 * BK, &Bh[nxt][1][0], wave, lane);
        __builtin_amdgcn_s_setprio(1);
#pragma unroll
        for (int s = 0; s < 4; ++s)
#pragma unroll
            for (int u = 0; u < 2; ++u)
#pragma unroll
                for (int st = 0; st < 2; ++st)
                    acc[s][u] = __builtin_amdgcn_mfma_f32_16x16x32_bf16(fA0[s][st], fB0[u][st], acc[s][u], 0, 0, 0);
        __builtin_amdgcn_s_setprio(0);

        // ---- P2: read A1(t); no stage, no vmcnt; MFMA A0xB1 ----
        BAR();
#pragma unroll
        for (int s = 0; s < 4; ++s)
#pragma unroll
            for (int st = 0; st < 2; ++st)
                fA1[s][st] = lds_frag(A1c, (s * 2 + wm) * 16, lr, st, ks, swz);
        __builtin_amdgcn_s_setprio(1);
#pragma unroll
        for (int s = 0; s < 4; ++s)
#pragma unroll
            for (int u = 0; u < 2; ++u)
#pragma unroll
                for (int st = 0; st < 2; ++st)
                    acc[s][2 + u] = __builtin_amdgcn_mfma_f32_16x16x32_bf16(fA0[s][st], fB1[u][st], acc[s][2 + u], 0, 0, 0);
        __builtin_amdgcn_s_setprio(0);

        // ---- P3: read A0(t+1); stage A0(t+2); MFMA A1xB0 ----
        BAR();
        WAITV(6);  // retires A0(t+1) (staged 4 phases ago)
#pragma unroll
        for (int s = 0; s < 4; ++s)
#pragma unroll
            for (int st = 0; st < 2; ++st)
                fA0[s][st] = lds_frag(A0n, (s * 2 + wm) * 16, lr, st, ks, swz);
        stage_half(Ab + t2 * BK, &Ah[cur][0][0], wave, lane);
        __builtin_amdgcn_s_setprio(1);
#pragma unroll
        for (int s = 0; s < 4; ++s)
#pragma unroll
            for (int u = 0; u < 2; ++u)
#pragma unroll
                for (int st = 0; st < 2; ++st)
                    acc[4 + s][u] = __builtin_amdgcn_mfma_f32_16x16x32_bf16(fA1[s][st], fB0[u][st], acc[4 + s][u], 0, 0, 0);
        __builtin_amdgcn_s_setprio(0);

        // ---- P4: read B0(t+1); stage B0(t+2); MFMA A1xB1 ----
        BAR();
        WAITV(6);  // retires B0(t+1) (staged 4 phases ago)
#pragma unroll
        for (int u = 0; u < 2; ++u)
#pragma unroll
            for (int st = 0; st < 2; ++st)
                fB0[u][st] = lds_frag(B0n, (u * 4 + wn) * 16, lr, st, ks, swz);
        stage_half(Bb + t2 * BK, &Bh[cur][0][0], wave, lane);
        __builtin_amdgcn_s_setprio(1);
#pragma unroll
        for (int s = 0; s < 4; ++s)
#pragma unroll
            for (int u = 0; u < 2; ++u)
#pragma unroll
                for (int st = 0; st < 2; ++st)
                    acc[4 + s][2 + u] = __builtin_amdgcn_mfma_f32_16x16x32_bf16(fA1[s][st], fB1[u][st], acc[4 + s][2 + u], 0, 0, 0);
        __builtin_amdgcn_s_setprio(0);
    }
    WAITV(0);  // drain tail dummy stages before epilogue/exit

    const int rsub = ks * 4;
#pragma unroll
    for (int f = 0; f < 8; ++f) {
        const int h = f >> 2, s = f & 3;
        const int rb = m0 + h * 128 + (s * 2 + wm) * 16 + rsub;
#pragma unroll
        for (int j = 0; j < 4; ++j) {
            const int r = rb + j;
            float bv = 0.f;
            if (EPI == 1) bv = bias[r];
#pragma unroll
            for (int g = 0; g < 4; ++g) {
                const int c = n0 + (g >> 1) * 128 + ((g & 1) * 4 + wn) * 16 + lr;
                const float v = acc[f][g][j] + bv;
                if (EPI == 1) ((bf16_t*)Call)[sC * z + (size_t)r * LD + c] = (bf16_t)v;
                else          ((float*)Call)[sC * z + (size_t)r * LD + c] = v;
            }
        }
    }
}

// ---------------- squared row norms of Kb/Qb (bf16 [N,C,B]) -> f32 [N,C] ----------------
__global__ void k_row_norm2(const bf16_t* __restrict__ Kb, const bf16_t* __restrict__ Qb,
                            float* __restrict__ DK2, float* __restrict__ DQ2) {
    const int row = blockIdx.x, n = blockIdx.y;
    const bf16_t* src = blockIdx.z ? Qb : Kb;
    float* dst = blockIdx.z ? DQ2 : DK2;
    const bf16_t* pr = src + ((size_t)n * CD + row) * BD + threadIdx.x * 8;
    bf16x8 v = *(const bf16x8*)pr;
    float s = 0.f;
#pragma unroll
    for (int e = 0; e < 8; ++e) { float x = (float)v[e]; s += x * x; }
#pragma unroll
    for (int off = 32; off; off >>= 1) s += __shfl_xor(s, off, 64);
    __shared__ float ws[4];
    if ((threadIdx.x & 63) == 0) ws[threadIdx.x >> 6] = s;
    __syncthreads();
    if (threadIdx.x == 0) dst[(size_t)n * CD + row] = ws[0] + ws[1] + ws[2] + ws[3];
}

// ------- per-row: scale by rsqrt(DQ2[i]*DK2[j]), softmax over i, write bf16 SMT[j,i] -------
__global__ void k_softmax_rows(const float* __restrict__ Yt, const float* __restrict__ DK2,
                               const float* __restrict__ DQ2, bf16_t* __restrict__ SMT) {
    const int j = blockIdx.x, n = blockIdx.y, t = threadIdx.x;
    const int lane = t & 63, wave = t >> 6;
    const float* y = Yt + ((size_t)n * CD + j) * CD;
    const float* q2 = DQ2 + (size_t)n * CD;
    const float dk2 = DK2[(size_t)n * CD + j];
    const int i0 = t * 8;

    float v[8];
    float4 a = *(const float4*)(y + i0);
    float4 b = *(const float4*)(y + i0 + 4);
    float4 qa = *(const float4*)(q2 + i0);
    float4 qb = *(const float4*)(q2 + i0 + 4);
    v[0] = a.x * rsqrtf(fmaxf(dk2 * qa.x, 1e-12f));
    v[1] = a.y * rsqrtf(fmaxf(dk2 * qa.y, 1e-12f));
    v[2] = a.z * rsqrtf(fmaxf(dk2 * qa.z, 1e-12f));
    v[3] = a.w * rsqrtf(fmaxf(dk2 * qa.w, 1e-12f));
    v[4] = b.x * rsqrtf(fmaxf(dk2 * qb.x, 1e-12f));
    v[5] = b.y * rsqrtf(fmaxf(dk2 * qb.y, 1e-12f));
    v[6] = b.z * rsqrtf(fmaxf(dk2 * qb.z, 1e-12f));
    v[7] = b.w * rsqrtf(fmaxf(dk2 * qb.w, 1e-12f));

    float m = v[0];
#pragma unroll
    for (int e = 1; e < 8; ++e) m = fmaxf(m, v[e]);
#pragma unroll
    for (int off = 32; off; off >>= 1) m = fmaxf(m, __shfl_xor(m, off, 64));
    __shared__ float redm[4], reds[4];
    if (lane == 0) redm[wave] = m;
    __syncthreads();
    m = fmaxf(fmaxf(redm[0], redm[1]), fmaxf(redm[2], redm[3]));

    float e8[8];
    float s = 0.f;
#pragma unroll
    for (int e = 0; e < 8; ++e) { e8[e] = __expf(v[e] - m); s += e8[e]; }
#pragma unroll
    for (int off = 32; off; off >>= 1) s += __shfl_xor(s, off, 64);
    if (lane == 0) reds[wave] = s;
    __syncthreads();
    s = reds[0] + reds[1] + reds[2] + reds[3];
    const float inv = 1.f / s;

    bf16x8 o;
#pragma unroll
    for (int e = 0; e < 8; ++e) o[e] = (bf16_t)(e8[e] * inv);
    *(bf16x8*)(SMT + ((size_t)n * CD + j) * CD + i0) = o;
}

extern "C" void kernel_launch(void* const* d_in, const int* in_sizes, int n_in,
                              void* d_out, int out_size, void* d_ws, size_t ws_size,
                              hipStream_t stream) {
    const float* X   = (const float*)d_in[0];
    const float* Wk  = (const float*)d_in[1];
    const float* Wq  = (const float*)d_in[2];
    const float* Wk0 = (const float*)d_in[3];
    const float* Wq0 = (const float*)d_in[4];
    float* Z = (float*)d_out;

    const size_t NCB = (size_t)NB * CD * BD;
    const size_t CC  = (size_t)CD * CD;
    const size_t NCC = (size_t)NB * CC;

    char* p = (char*)d_ws;
    bf16_t* XbT = (bf16_t*)p; p += NCB * 2;
    bf16_t* Wkb = (bf16_t*)p; p += CC * 2;
    bf16_t* Wqb = (bf16_t*)p; p += CC * 2;
    bf16_t* Kb  = (bf16_t*)p; p += NCB * 2;
    bf16_t* Qb  = (bf16_t*)p; p += NCB * 2;
    float*  DK2 = (float*)p;  p += (size_t)NB * CD * 4;
    float*  DQ2 = (float*)p;  p += (size_t)NB * CD * 4;
    float*  Yt  = (float*)p;  p += NCC * 4;
    bf16_t* SMT = Kb;  // Kb dead after Yt; reuse
    if ((size_t)(p - (char*)d_ws) > ws_size) return;

    dim3 blk(256);
    k_transpose_x<<<dim3(BD / 64, CD / 64, NB), blk, 0, stream>>>(X, XbT);
    k_convert_w<<<dim3(CC / 1024, 2), blk, 0, stream>>>(Wk, Wq, Wkb, Wqb);
    k_gemm256<1><<<512, 512, 0, stream>>>(Wkb, 0, XbT, (size_t)BD * CD, Kb, (size_t)CD * BD, Wk0);
    k_gemm256<1><<<512, 512, 0, stream>>>(Wqb, 0, XbT, (size_t)BD * CD, Qb, (size_t)CD * BD, Wq0);
    k_row_norm2<<<dim3(CD, NB, 2), blk, 0, stream>>>(Kb, Qb, DK2, DQ2);
    k_gemm256<0><<<512, 512, 0, stream>>>(Kb, (size_t)CD * BD, Qb, (size_t)CD * BD, Yt, CC, nullptr);
    k_softmax_rows<<<dim3(CD, NB), blk, 0, stream>>>(Yt, DK2, DQ2, SMT);
    k_gemm256<0><<<512, 512, 0, stream>>>(SMT, CC, XbT, (size_t)BD * CD, Z, (size_t)CD * BD, nullptr);
}